// Round 1
// baseline (1216.891 us; speedup 1.0000x reference)
//
#include <hip/hip_runtime.h>
#include <math.h>

// Problem constants
#define B_ 64
#define J_ 512
#define D_ 1024

// GEMM tile config
#define MT 64     // rows per block
#define NT 64     // cols per n-tile
#define KT 32     // k per k-tile
#define PAD 68    // padded row length for [k][m]/[k][n] LDS tiles (16B-aligned stride, low conflict)

// tanh via exp2-based __expf: tanh(x) = 1 - 2/(1+e^{2x}); saturates correctly for |x| large.
__device__ __forceinline__ float fast_tanh(float x) {
    return 1.0f - 2.0f / (1.0f + __expf(2.0f * x));
}

__global__ __launch_bounds__(256) void score_kernel(
    const float* __restrict__ x, const float* __restrict__ mask,
    const float* __restrict__ W1, const float* __restrict__ b1,
    const float* __restrict__ W2, const float* __restrict__ b2,
    float* __restrict__ val_ws, float* __restrict__ pooled)
{
    __shared__ float As[KT][PAD];   // transposed: As[k][row]
    __shared__ float Bs[KT][PAD];   // Bs[k][col]
    __shared__ float red[MT][17];   // pv reduction across tx
    __shared__ float vrow[MT];      // per-row val for pooled accumulation

    const int tid = threadIdx.x;
    const int tx = tid & 15;        // col group (4 cols)
    const int ty = tid >> 4;        // row group (4 rows)
    const int r0 = blockIdx.x * MT; // 64 rows, all within one batch (512 % 64 == 0)
    const int b  = r0 >> 9;         // r0 / 512

    float pv[4] = {0.f, 0.f, 0.f, 0.f};  // per-thread partial of h@W2 for its 4 rows

    for (int n0 = 0; n0 < D_; n0 += NT) {
        float acc[4][4];
        #pragma unroll
        for (int i = 0; i < 4; ++i)
            #pragma unroll
            for (int j = 0; j < 4; ++j) acc[i][j] = 0.f;

        for (int k0 = 0; k0 < D_; k0 += KT) {
            // Stage A tile: X[r0..r0+63][k0..k0+31] -> As[k][row] (transposed scatter)
            #pragma unroll
            for (int l = 0; l < 2; ++l) {
                const int f   = tid + l * 256;     // 0..511
                const int row = f >> 3;            // 0..63
                const int k4  = (f & 7) << 2;      // 0,4,..,28
                const float4 xv = *reinterpret_cast<const float4*>(
                    &x[(size_t)(r0 + row) * D_ + k0 + k4]);
                As[k4 + 0][row] = xv.x;
                As[k4 + 1][row] = xv.y;
                As[k4 + 2][row] = xv.z;
                As[k4 + 3][row] = xv.w;
            }
            // Stage B tile: W1[k0..k0+31][n0..n0+63] -> Bs[k][n] (direct float4)
            #pragma unroll
            for (int l = 0; l < 2; ++l) {
                const int f  = tid + l * 256;      // 0..511
                const int k  = f >> 4;             // 0..31
                const int n4 = (f & 15) << 2;      // 0,4,..,60
                const float4 wv = *reinterpret_cast<const float4*>(
                    &W1[(size_t)(k0 + k) * D_ + n0 + n4]);
                *reinterpret_cast<float4*>(&Bs[k][n4]) = wv;
            }
            __syncthreads();

            #pragma unroll
            for (int kk = 0; kk < KT; ++kk) {
                const float4 a4 = *reinterpret_cast<const float4*>(&As[kk][ty << 2]);
                const float4 b4 = *reinterpret_cast<const float4*>(&Bs[kk][tx << 2]);
                const float av[4] = {a4.x, a4.y, a4.z, a4.w};
                const float bv[4] = {b4.x, b4.y, b4.z, b4.w};
                #pragma unroll
                for (int i = 0; i < 4; ++i)
                    #pragma unroll
                    for (int j = 0; j < 4; ++j)
                        acc[i][j] = fmaf(av[i], bv[j], acc[i][j]);
            }
            __syncthreads();
        }

        // Fold this n-tile of h into pv: pv[i] += tanh(acc + b1) * W2
        #pragma unroll
        for (int j = 0; j < 4; ++j) {
            const int col = n0 + (tx << 2) + j;
            const float b1v = b1[col];
            const float w2v = W2[col];
            #pragma unroll
            for (int i = 0; i < 4; ++i) {
                const float h = fast_tanh(acc[i][j] + b1v);
                pv[i] = fmaf(h, w2v, pv[i]);
            }
        }
    }

    // Reduce pv across the 16 tx threads sharing each row
    #pragma unroll
    for (int i = 0; i < 4; ++i) red[(ty << 2) + i][tx] = pv[i];
    __syncthreads();

    if (tid < MT) {
        float s = 0.f;
        #pragma unroll
        for (int t = 0; t < 16; ++t) s += red[tid][t];
        const float z  = s + b2[0];
        const float sg = 1.0f / (1.0f + __expf(-z));
        const float v  = sg * mask[r0 + tid];
        val_ws[r0 + tid] = v;
        vrow[tid] = v;
    }
    __syncthreads();

    // Unnormalized pooled: pooled_un[b,k] += sum over this block's 64 rows of x[r,k]*val[r]
    // (normalization by inv_sum commutes; applied in finalize_kernel)
    const int k = tid << 2;
    float a0 = 0.f, a1 = 0.f, a2 = 0.f, a3 = 0.f;
    for (int row = 0; row < MT; ++row) {
        const float v = vrow[row];
        const float4 xv = *reinterpret_cast<const float4*>(
            &x[(size_t)(r0 + row) * D_ + k]);
        a0 = fmaf(xv.x, v, a0);
        a1 = fmaf(xv.y, v, a1);
        a2 = fmaf(xv.z, v, a2);
        a3 = fmaf(xv.w, v, a3);
    }
    float* pb = &pooled[b * D_ + k];
    atomicAdd(pb + 0, a0);
    atomicAdd(pb + 1, a1);
    atomicAdd(pb + 2, a2);
    atomicAdd(pb + 3, a3);
}

__global__ __launch_bounds__(256) void finalize_kernel(
    const float* __restrict__ val_ws, const float* __restrict__ pooled,
    const float* __restrict__ W3, const float* __restrict__ b3,
    float* __restrict__ out)
{
    __shared__ float sred[256];
    const int b = blockIdx.x;
    const int tid = threadIdx.x;

    // Per-batch sum of val over J=512
    const float v0 = val_ws[b * J_ + tid];
    const float v1 = val_ws[b * J_ + 256 + tid];
    sred[tid] = v0 + v1;
    __syncthreads();
    for (int s = 128; s > 0; s >>= 1) {
        if (tid < s) sred[tid] += sred[tid + s];
        __syncthreads();
    }
    const float inv = 1.0f / sred[0];

    // att_weights -> out[192 ..]
    out[192 + b * J_ + tid]       = v0 * inv;
    out[192 + b * J_ + 256 + tid] = v1 * inv;

    // output_val = (pooled_un * inv) @ W3 + b3
    const int k = tid << 2;
    float acc3[3] = {0.f, 0.f, 0.f};
    #pragma unroll
    for (int c = 0; c < 4; ++c) {
        const float p = pooled[b * D_ + k + c] * inv;
        acc3[0] = fmaf(p, W3[(k + c) * 3 + 0], acc3[0]);
        acc3[1] = fmaf(p, W3[(k + c) * 3 + 1], acc3[1]);
        acc3[2] = fmaf(p, W3[(k + c) * 3 + 2], acc3[2]);
    }
    for (int o = 0; o < 3; ++o) {
        __syncthreads();
        sred[tid] = acc3[o];
        __syncthreads();
        for (int s = 128; s > 0; s >>= 1) {
            if (tid < s) sred[tid] += sred[tid + s];
            __syncthreads();
        }
        if (tid == 0) out[b * 3 + o] = sred[0] + b3[o];
    }
}

extern "C" void kernel_launch(void* const* d_in, const int* in_sizes, int n_in,
                              void* d_out, int out_size, void* d_ws, size_t ws_size,
                              hipStream_t stream) {
    const float* x    = (const float*)d_in[0];
    const float* mask = (const float*)d_in[1];
    const float* W1   = (const float*)d_in[2];
    const float* b1   = (const float*)d_in[3];
    const float* W2   = (const float*)d_in[4];
    const float* b2   = (const float*)d_in[5];
    const float* W3   = (const float*)d_in[6];
    const float* b3   = (const float*)d_in[7];
    float* out = (float*)d_out;

    float* val_ws = (float*)d_ws;            // B*J floats
    float* pooled = val_ws + B_ * J_;        // B*D floats (unnormalized pooled)

    // ws is poisoned 0xAA before every timed call: zero the atomic accumulator.
    hipMemsetAsync(pooled, 0, (size_t)B_ * D_ * sizeof(float), stream);

    score_kernel<<<dim3((B_ * J_) / MT), dim3(256), 0, stream>>>(
        x, mask, W1, b1, W2, b2, val_ws, pooled);
    finalize_kernel<<<dim3(B_), dim3(256), 0, stream>>>(
        val_ws, pooled, W3, b3, out);
}

// Round 2
// 306.096 us; speedup vs baseline: 3.9755x; 3.9755x over previous
//
#include <hip/hip_runtime.h>
#include <math.h>
#include <stdint.h>

#define B_ 64
#define J_ 512
#define D_ 1024

typedef __attribute__((ext_vector_type(8))) short short8;
typedef __attribute__((ext_vector_type(4))) float f32x4;

#define GLOBAL_AS __attribute__((address_space(1)))
#define LDS_AS    __attribute__((address_space(3)))

__device__ __forceinline__ void async16(const void* g, void* l) {
    __builtin_amdgcn_global_load_lds((const GLOBAL_AS uint32_t*)g,
                                     (LDS_AS uint32_t*)l, 16, 0, 0);
}

// tanh(x) = 1 - 2/(1+e^{2x}); saturates correctly for |x| large.
__device__ __forceinline__ float fast_tanh(float x) {
    return 1.0f - 2.0f / (1.0f + __expf(2.0f * x));
}

// fp32 -> bf16 round-to-nearest-even
__device__ __forceinline__ unsigned short f2bf(float f) {
    uint32_t u = __builtin_bit_cast(uint32_t, f);
    u += 0x7fffu + ((u >> 16) & 1u);
    return (unsigned short)(u >> 16);
}

// ---------------------------------------------------------------------------
// Fast path kernels (bf16 MFMA)
// ---------------------------------------------------------------------------

__global__ __launch_bounds__(256) void cast_x_kernel(const float* __restrict__ x,
                                                     unsigned short* __restrict__ xb) {
    const size_t i = ((size_t)blockIdx.x * 256 + threadIdx.x) * 8;
    const float4 v0 = *reinterpret_cast<const float4*>(x + i);
    const float4 v1 = *reinterpret_cast<const float4*>(x + i + 4);
    uint4 o;
    o.x = (uint32_t)f2bf(v0.x) | ((uint32_t)f2bf(v0.y) << 16);
    o.y = (uint32_t)f2bf(v0.z) | ((uint32_t)f2bf(v0.w) << 16);
    o.z = (uint32_t)f2bf(v1.x) | ((uint32_t)f2bf(v1.y) << 16);
    o.w = (uint32_t)f2bf(v1.z) | ((uint32_t)f2bf(v1.w) << 16);
    *reinterpret_cast<uint4*>(xb + i) = o;
}

// W1[k][n] fp32 -> W1t[n][k] bf16 (so B-operand frags are contiguous in k)
__global__ __launch_bounds__(256) void transpose_cast_w1(const float* __restrict__ W1,
                                                         unsigned short* __restrict__ W1t) {
    __shared__ float t[32][33];
    const int n = blockIdx.x * 32 + threadIdx.x;
    for (int i = threadIdx.y; i < 32; i += 8)
        t[i][threadIdx.x] = W1[(size_t)(blockIdx.y * 32 + i) * D_ + n];
    __syncthreads();
    const int k = blockIdx.y * 32 + threadIdx.x;
    for (int i = threadIdx.y; i < 32; i += 8)
        W1t[(size_t)(blockIdx.x * 32 + i) * D_ + k] = f2bf(t[threadIdx.x][i]);
}

// Block tile: 64(M) x 256(N), BK=64, 8 waves each 64x32 (wave grid 1x8 over N).
// Full-N sweep per block -> per-row pv completes in-block; fused sigmoid/mask
// and unnormalized pooling (normalization commutes to finalize).
__global__ __launch_bounds__(512, 4) void gemm_score_kernel(
    const unsigned short* __restrict__ Xb, const unsigned short* __restrict__ W1t,
    const float* __restrict__ b1, const float* __restrict__ W2,
    const float* __restrict__ b2, const float* __restrict__ mask,
    float* __restrict__ val_ws, float* __restrict__ pooled)
{
    __shared__ __align__(16) unsigned short ldsA[64 * 64];    // [m][k], k-chunk swizzled
    __shared__ __align__(16) unsigned short ldsB[256 * 64];   // [n][k], k-chunk swizzled
    __shared__ float b1s[D_], w2s[D_];
    __shared__ float pv_part[8][64];
    __shared__ float vrow[64];

    const int tid  = threadIdx.x;
    const int wave = tid >> 6;
    const int l    = tid & 63;
    const int wn   = wave;            // wave grid 1(M) x 8(N)
    const int l15  = l & 15;
    const int kgrp = l >> 4;
    const int l7   = l & 7;
    const int r0   = blockIdx.x * 64; // 64 rows per block, within one batch
    const int bb   = r0 >> 9;

    b1s[tid] = b1[tid]; b1s[tid + 512] = b1[tid + 512];
    w2s[tid] = W2[tid]; w2s[tid + 512] = W2[tid + 512];

    // --- staging pointers (global_load_lds: wave-uniform LDS base + lane*16) ---
    // A tile 64x64 bf16 = 8 KB = 1 instr/thread
    const int arow = tid >> 3;
    const int achv = ((tid & 7) ^ (arow & 7)) << 3;   // swizzled k-chunk
    const unsigned short* gA = Xb + (size_t)(r0 + arow) * D_ + achv;
    unsigned short* lA = ldsA + (wave << 9);
    // B tile 256x64 bf16 = 32 KB = 4 instr/thread
    const unsigned short* gB[4];
    unsigned short* lB[4];
    #pragma unroll
    for (int t = 0; t < 4; ++t) {
        const int f = tid + t * 512;
        const int row = f >> 3;
        const int ch = ((f & 7) ^ (row & 7)) << 3;
        gB[t] = W1t + (size_t)row * D_ + ch;
        lB[t] = ldsB + t * 4096 + (wave << 9);
    }

    // --- fragment LDS offsets (ushort units), swizzle-consistent ---
    int aoff[4][2], boff[2][2];
    #pragma unroll
    for (int mi = 0; mi < 4; ++mi)
        #pragma unroll
        for (int ks = 0; ks < 2; ++ks)
            aoff[mi][ks] = (mi * 16 + l15) * 64 + (((ks * 4 + kgrp) ^ l7) << 3);
    #pragma unroll
    for (int ni = 0; ni < 2; ++ni)
        #pragma unroll
        for (int ks = 0; ks < 2; ++ks)
            boff[ni][ks] = (wn * 32 + ni * 16 + l15) * 64 + (((ks * 4 + kgrp) ^ l7) << 3);

    float pv[4][4];
    #pragma unroll
    for (int mi = 0; mi < 4; ++mi)
        #pragma unroll
        for (int r = 0; r < 4; ++r) pv[mi][r] = 0.f;

    for (int n0 = 0; n0 < 4; ++n0) {
        f32x4 acc[4][2];
        #pragma unroll
        for (int mi = 0; mi < 4; ++mi)
            #pragma unroll
            for (int ni = 0; ni < 2; ++ni)
                acc[mi][ni] = (f32x4){0.f, 0.f, 0.f, 0.f};

        const size_t bofs = (size_t)n0 * 256 * D_;
        for (int k0 = 0; k0 < D_; k0 += 64) {
            async16(gA + k0, lA);
            #pragma unroll
            for (int t = 0; t < 4; ++t) async16(gB[t] + bofs + k0, lB[t]);
            __syncthreads();
            #pragma unroll
            for (int ks = 0; ks < 2; ++ks) {
                const short8 a0 = *reinterpret_cast<const short8*>(ldsA + aoff[0][ks]);
                const short8 a1 = *reinterpret_cast<const short8*>(ldsA + aoff[1][ks]);
                const short8 a2 = *reinterpret_cast<const short8*>(ldsA + aoff[2][ks]);
                const short8 a3 = *reinterpret_cast<const short8*>(ldsA + aoff[3][ks]);
                const short8 b0 = *reinterpret_cast<const short8*>(ldsB + boff[0][ks]);
                const short8 b1f = *reinterpret_cast<const short8*>(ldsB + boff[1][ks]);
                acc[0][0] = __builtin_amdgcn_mfma_f32_16x16x32_bf16(a0, b0,  acc[0][0], 0, 0, 0);
                acc[1][0] = __builtin_amdgcn_mfma_f32_16x16x32_bf16(a1, b0,  acc[1][0], 0, 0, 0);
                acc[2][0] = __builtin_amdgcn_mfma_f32_16x16x32_bf16(a2, b0,  acc[2][0], 0, 0, 0);
                acc[3][0] = __builtin_amdgcn_mfma_f32_16x16x32_bf16(a3, b0,  acc[3][0], 0, 0, 0);
                acc[0][1] = __builtin_amdgcn_mfma_f32_16x16x32_bf16(a0, b1f, acc[0][1], 0, 0, 0);
                acc[1][1] = __builtin_amdgcn_mfma_f32_16x16x32_bf16(a1, b1f, acc[1][1], 0, 0, 0);
                acc[2][1] = __builtin_amdgcn_mfma_f32_16x16x32_bf16(a2, b1f, acc[2][1], 0, 0, 0);
                acc[3][1] = __builtin_amdgcn_mfma_f32_16x16x32_bf16(a3, b1f, acc[3][1], 0, 0, 0);
            }
            __syncthreads();
        }

        // fold this 256-col n-tile of h into pv (h never materialized)
        #pragma unroll
        for (int ni = 0; ni < 2; ++ni) {
            const int col = n0 * 256 + wn * 32 + ni * 16 + l15;
            const float b1v = b1s[col];
            const float w2v = w2s[col];
            #pragma unroll
            for (int mi = 0; mi < 4; ++mi)
                #pragma unroll
                for (int r = 0; r < 4; ++r) {
                    const float h = fast_tanh(acc[mi][ni][r] + b1v);
                    pv[mi][r] = fmaf(h, w2v, pv[mi][r]);
                }
        }
    }

    // reduce pv over the 16 col-lanes (C/D layout: row = kgrp*4+r, col = l15)
    #pragma unroll
    for (int mi = 0; mi < 4; ++mi)
        #pragma unroll
        for (int r = 0; r < 4; ++r) {
            float s = pv[mi][r];
            s += __shfl_xor(s, 1);
            s += __shfl_xor(s, 2);
            s += __shfl_xor(s, 4);
            s += __shfl_xor(s, 8);
            if (l15 == 0) pv_part[wn][mi * 16 + kgrp * 4 + r] = s;
        }
    __syncthreads();
    if (tid < 64) {
        float s = b2[0];
        #pragma unroll
        for (int w = 0; w < 8; ++w) s += pv_part[w][tid];
        const float sg = 1.0f / (1.0f + __expf(-s));
        const float v = sg * mask[r0 + tid];
        val_ws[r0 + tid] = v;
        vrow[tid] = v;
    }
    __syncthreads();

    // unnormalized pooled: pooled[bb][k] += sum_rows Xb[r][k]*val[r]
    const int kc = tid << 1;
    float a0 = 0.f, a1 = 0.f;
    for (int row = 0; row < 64; ++row) {
        const float v = vrow[row];
        const uint32_t u = *reinterpret_cast<const uint32_t*>(
            Xb + (size_t)(r0 + row) * D_ + kc);
        const float x0 = __builtin_bit_cast(float, u << 16);
        const float x1 = __builtin_bit_cast(float, u & 0xffff0000u);
        a0 = fmaf(x0, v, a0);
        a1 = fmaf(x1, v, a1);
    }
    atomicAdd(&pooled[bb * D_ + kc], a0);
    atomicAdd(&pooled[bb * D_ + kc + 1], a1);
}

// ---------------------------------------------------------------------------
// Fallback fp32 path (round-1 kernel, used only if ws too small)
// ---------------------------------------------------------------------------
#define MT 64
#define KT 32
#define PAD 68

__global__ __launch_bounds__(256) void score_kernel_fp32(
    const float* __restrict__ x, const float* __restrict__ mask,
    const float* __restrict__ W1, const float* __restrict__ b1,
    const float* __restrict__ W2, const float* __restrict__ b2,
    float* __restrict__ val_ws, float* __restrict__ pooled)
{
    __shared__ float As[KT][PAD];
    __shared__ float Bs[KT][PAD];
    __shared__ float red[MT][17];
    __shared__ float vrow[MT];

    const int tid = threadIdx.x;
    const int tx = tid & 15;
    const int ty = tid >> 4;
    const int r0 = blockIdx.x * MT;
    const int b  = r0 >> 9;

    float pv[4] = {0.f, 0.f, 0.f, 0.f};

    for (int n0 = 0; n0 < D_; n0 += 64) {
        float acc[4][4];
        #pragma unroll
        for (int i = 0; i < 4; ++i)
            #pragma unroll
            for (int j = 0; j < 4; ++j) acc[i][j] = 0.f;

        for (int k0 = 0; k0 < D_; k0 += KT) {
            #pragma unroll
            for (int ll = 0; ll < 2; ++ll) {
                const int f   = tid + ll * 256;
                const int row = f >> 3;
                const int k4  = (f & 7) << 2;
                const float4 xv = *reinterpret_cast<const float4*>(
                    &x[(size_t)(r0 + row) * D_ + k0 + k4]);
                As[k4 + 0][row] = xv.x;
                As[k4 + 1][row] = xv.y;
                As[k4 + 2][row] = xv.z;
                As[k4 + 3][row] = xv.w;
            }
            #pragma unroll
            for (int ll = 0; ll < 2; ++ll) {
                const int f  = tid + ll * 256;
                const int k  = f >> 4;
                const int n4 = (f & 15) << 2;
                const float4 wv = *reinterpret_cast<const float4*>(
                    &W1[(size_t)(k0 + k) * D_ + n0 + n4]);
                *reinterpret_cast<float4*>(&Bs[k][n4]) = wv;
            }
            __syncthreads();
            #pragma unroll
            for (int kk = 0; kk < KT; ++kk) {
                const float4 a4 = *reinterpret_cast<const float4*>(&As[kk][ty << 2]);
                const float4 b4 = *reinterpret_cast<const float4*>(&Bs[kk][tx << 2]);
                const float av[4] = {a4.x, a4.y, a4.z, a4.w};
                const float bv[4] = {b4.x, b4.y, b4.z, b4.w};
                #pragma unroll
                for (int i = 0; i < 4; ++i)
                    #pragma unroll
                    for (int j = 0; j < 4; ++j)
                        acc[i][j] = fmaf(av[i], bv[j], acc[i][j]);
            }
            __syncthreads();
        }
        #pragma unroll
        for (int j = 0; j < 4; ++j) {
            const int col = n0 + (tx << 2) + j;
            const float b1v = b1[col];
            const float w2v = W2[col];
            #pragma unroll
            for (int i = 0; i < 4; ++i) {
                const float h = fast_tanh(acc[i][j] + b1v);
                pv[i] = fmaf(h, w2v, pv[i]);
            }
        }
    }

    #pragma unroll
    for (int i = 0; i < 4; ++i) red[(ty << 2) + i][tx] = pv[i];
    __syncthreads();

    if (tid < MT) {
        float s = 0.f;
        #pragma unroll
        for (int t = 0; t < 16; ++t) s += red[tid][t];
        const float z  = s + b2[0];
        const float sg = 1.0f / (1.0f + __expf(-z));
        const float v  = sg * mask[r0 + tid];
        val_ws[r0 + tid] = v;
        vrow[tid] = v;
    }
    __syncthreads();

    const int k = tid << 2;
    float a0 = 0.f, a1 = 0.f, a2 = 0.f, a3 = 0.f;
    for (int row = 0; row < MT; ++row) {
        const float v = vrow[row];
        const float4 xv = *reinterpret_cast<const float4*>(
            &x[(size_t)(r0 + row) * D_ + k]);
        a0 = fmaf(xv.x, v, a0);
        a1 = fmaf(xv.y, v, a1);
        a2 = fmaf(xv.z, v, a2);
        a3 = fmaf(xv.w, v, a3);
    }
    float* pb = &pooled[b * D_ + k];
    atomicAdd(pb + 0, a0);
    atomicAdd(pb + 1, a1);
    atomicAdd(pb + 2, a2);
    atomicAdd(pb + 3, a3);
}

__global__ __launch_bounds__(256) void finalize_kernel(
    const float* __restrict__ val_ws, const float* __restrict__ pooled,
    const float* __restrict__ W3, const float* __restrict__ b3,
    float* __restrict__ out)
{
    __shared__ float sred[256];
    const int b = blockIdx.x;
    const int tid = threadIdx.x;

    const float v0 = val_ws[b * J_ + tid];
    const float v1 = val_ws[b * J_ + 256 + tid];
    sred[tid] = v0 + v1;
    __syncthreads();
    for (int s = 128; s > 0; s >>= 1) {
        if (tid < s) sred[tid] += sred[tid + s];
        __syncthreads();
    }
    const float inv = 1.0f / sred[0];

    out[192 + b * J_ + tid]       = v0 * inv;
    out[192 + b * J_ + 256 + tid] = v1 * inv;

    const int k = tid << 2;
    float acc3[3] = {0.f, 0.f, 0.f};
    #pragma unroll
    for (int c = 0; c < 4; ++c) {
        const float p = pooled[b * D_ + k + c] * inv;
        acc3[0] = fmaf(p, W3[(k + c) * 3 + 0], acc3[0]);
        acc3[1] = fmaf(p, W3[(k + c) * 3 + 1], acc3[1]);
        acc3[2] = fmaf(p, W3[(k + c) * 3 + 2], acc3[2]);
    }
    for (int o = 0; o < 3; ++o) {
        __syncthreads();
        sred[tid] = acc3[o];
        __syncthreads();
        for (int s = 128; s > 0; s >>= 1) {
            if (tid < s) sred[tid] += sred[tid + s];
            __syncthreads();
        }
        if (tid == 0) out[b * 3 + o] = sred[0] + b3[o];
    }
}

extern "C" void kernel_launch(void* const* d_in, const int* in_sizes, int n_in,
                              void* d_out, int out_size, void* d_ws, size_t ws_size,
                              hipStream_t stream) {
    const float* x    = (const float*)d_in[0];
    const float* mask = (const float*)d_in[1];
    const float* W1   = (const float*)d_in[2];
    const float* b1   = (const float*)d_in[3];
    const float* W2   = (const float*)d_in[4];
    const float* b2   = (const float*)d_in[5];
    const float* W3   = (const float*)d_in[6];
    const float* b3   = (const float*)d_in[7];
    float* out = (float*)d_out;

    const size_t XB_BYTES   = (size_t)B_ * J_ * D_ * 2;   // 67,108,864
    const size_t W1T_BYTES  = (size_t)D_ * D_ * 2;        //  2,097,152
    const size_t VAL_BYTES  = (size_t)B_ * J_ * 4;        //    131,072
    const size_t POOL_BYTES = (size_t)B_ * D_ * 4;        //    262,144
    const size_t NEED = XB_BYTES + W1T_BYTES + VAL_BYTES + POOL_BYTES;

    if (ws_size >= NEED) {
        unsigned short* Xb  = (unsigned short*)d_ws;
        unsigned short* W1t = (unsigned short*)((char*)d_ws + XB_BYTES);
        float* val_ws = (float*)((char*)d_ws + XB_BYTES + W1T_BYTES);
        float* pooled = (float*)((char*)d_ws + XB_BYTES + W1T_BYTES + VAL_BYTES);

        hipMemsetAsync(pooled, 0, POOL_BYTES, stream);
        cast_x_kernel<<<(B_ * J_ * D_) / (256 * 8), 256, 0, stream>>>(x, Xb);
        transpose_cast_w1<<<dim3(32, 32), dim3(32, 8), 0, stream>>>(W1, W1t);
        gemm_score_kernel<<<512, 512, 0, stream>>>(Xb, W1t, b1, W2, b2, mask,
                                                   val_ws, pooled);
        finalize_kernel<<<B_, 256, 0, stream>>>(val_ws, pooled, W3, b3, out);
    } else {
        float* val_ws = (float*)d_ws;
        float* pooled = val_ws + B_ * J_;
        hipMemsetAsync(pooled, 0, POOL_BYTES, stream);
        score_kernel_fp32<<<(B_ * J_) / MT, 256, 0, stream>>>(
            x, mask, W1, b1, W2, b2, val_ws, pooled);
        finalize_kernel<<<B_, 256, 0, stream>>>(val_ws, pooled, W3, b3, out);
    }
}